// Round 14
// baseline (220.549 us; speedup 1.0000x reference)
//
#include <hip/hip_runtime.h>
#include <hip/hip_bf16.h>
#include <stdint.h>

typedef int i32x4 __attribute__((ext_vector_type(4)));

#define K_DIM 2048
#define M_DIM 8192   // B*S = 4*2048 tokens
#define N_DIM 8192   // D_OUT
#define QBF   127.0f
#define EPSF  1e-5f
#define NT    32     // K_DIM / 64 sub-tiles (BK=64)

__device__ __forceinline__ void load_lds16(const void* gsrc, void* ldst) {
    __builtin_amdgcn_global_load_lds(
        (__attribute__((address_space(1))) void*)gsrc,
        (__attribute__((address_space(3))) void*)ldst,
        16, 0, 0);
}

// ---------- Kernel 1: deterministic partial |W| sums ----------
__global__ __launch_bounds__(256) void k_abs_partial(const float* __restrict__ w,
                                                     float* __restrict__ partial) {
    __shared__ float red[256];
    int t = threadIdx.x, b = blockIdx.x;
    const float4* w4 = (const float4*)w;
    size_t base = (size_t)b * 2048;
    float s = 0.f;
#pragma unroll
    for (int j = 0; j < 8; ++j) {
        float4 v = w4[base + j * 256 + t];
        s += fabsf(v.x) + fabsf(v.y) + fabsf(v.z) + fabsf(v.w);
    }
    red[t] = s; __syncthreads();
    for (int off = 128; off > 0; off >>= 1) {
        if (t < off) red[t] += red[t + off];
        __syncthreads();
    }
    if (t == 0) partial[b] = red[0];
}

// ---------- Kernel 2: gamma = sum(partial)/count ----------
__global__ __launch_bounds__(256) void k_gamma(const float* __restrict__ partial,
                                               float* __restrict__ gamma) {
    __shared__ float red[256];
    int t = threadIdx.x;
    float s = 0.f;
#pragma unroll
    for (int j = 0; j < 8; ++j) s += partial[t + j * 256];
    red[t] = s; __syncthreads();
    for (int off = 128; off > 0; off >>= 1) {
        if (t < off) red[t] += red[t + off];
        __syncthreads();
    }
    if (t == 0) gamma[0] = red[0] / 16777216.0f;
}

// ---------- Kernel 3: ternary-quantize W -> int8 ----------
__global__ __launch_bounds__(256) void k_quant_w(const float* __restrict__ w,
                                                 const float* __restrict__ gamma,
                                                 uint* __restrict__ wq) {
    float g = fmaxf(gamma[0], EPSF);
    int tid = blockIdx.x * 256 + threadIdx.x;    // 4,194,304 threads
    float4 v = ((const float4*)w)[tid];
    int a = (int)fminf(fmaxf(rintf(v.x / g), -1.f), 1.f);
    int b = (int)fminf(fmaxf(rintf(v.y / g), -1.f), 1.f);
    int c = (int)fminf(fmaxf(rintf(v.z / g), -1.f), 1.f);
    int d = (int)fminf(fmaxf(rintf(v.w / g), -1.f), 1.f);
    wq[tid] = (a & 255) | ((b & 255) << 8) | ((c & 255) << 16) | ((d & 255) << 24);
}

// ---------- Kernel 4: per-token absmax-quantize x -> int8, alpha ----------
__global__ __launch_bounds__(256) void k_quant_x(const float* __restrict__ x,
                                                 uint* __restrict__ xq,
                                                 float* __restrict__ alpha) {
    __shared__ float red[256];
    int t = threadIdx.x, row = blockIdx.x;
    const float4* x4 = (const float4*)x + (size_t)row * 512;
    float4 v0 = x4[t], v1 = x4[t + 256];
    float m = fmaxf(fmaxf(fabsf(v0.x), fabsf(v0.y)), fmaxf(fabsf(v0.z), fabsf(v0.w)));
    m = fmaxf(m, fmaxf(fmaxf(fabsf(v1.x), fabsf(v1.y)), fmaxf(fabsf(v1.z), fabsf(v1.w))));
    red[t] = m; __syncthreads();
    for (int off = 128; off > 0; off >>= 1) {
        if (t < off) red[t] = fmaxf(red[t], red[t + off]);
        __syncthreads();
    }
    float a = red[0];
    if (t == 0) alpha[row] = a;
    float den = fmaxf(a, EPSF);
    uint* q = xq + (size_t)row * 512;
    int q0 = (int)fminf(fmaxf(rintf(v0.x * QBF / den), -QBF), QBF);
    int q1 = (int)fminf(fmaxf(rintf(v0.y * QBF / den), -QBF), QBF);
    int q2 = (int)fminf(fmaxf(rintf(v0.z * QBF / den), -QBF), QBF);
    int q3 = (int)fminf(fmaxf(rintf(v0.w * QBF / den), -QBF), QBF);
    q[t] = (q0 & 255) | ((q1 & 255) << 8) | ((q2 & 255) << 16) | ((q3 & 255) << 24);
    q0 = (int)fminf(fmaxf(rintf(v1.x * QBF / den), -QBF), QBF);
    q1 = (int)fminf(fmaxf(rintf(v1.y * QBF / den), -QBF), QBF);
    q2 = (int)fminf(fmaxf(rintf(v1.z * QBF / den), -QBF), QBF);
    q3 = (int)fminf(fmaxf(rintf(v1.w * QBF / den), -QBF), QBF);
    q[t + 256] = (q0 & 255) | ((q1 & 255) << 8) | ((q2 & 255) << 16) | ((q3 & 255) << 24);
}

// ---------- Kernel 5: 256x256 i8 GEMM, barrier-free fat-wave ----------
// 256 thr = 4 waves (2x2), wave tile 128x128 (acc 8x8 16x16 frags = 256 VGPR),
// 1 wave/SIMD. ZERO s_barrier: each wave PRIVATELY stages its own A-half
// (rows wr*128..+127) + B-half (wc*128..+127), 16KB/subtile, R4's coalesced
// 16-row-region pattern + proven 0-conflict swizzle (phys chunk = logical ^
// ((row>>1)&3)). The x2 global re-read across the two waves sharing a panel is
// L1-absorbed (16KB unique/subtile < 32KB L1). Ring depth 2 = 32KB/wave =
// 128KB/block, 1 block/CU.
// Why this beats 6 failed schedules: block barriers locked all waves into
// read-phase/MFMA-phase alternation (sum, not max). Here overlap is intra-wave
// ILP: 16 ds_reads issued ahead, counted lgkmcnt(8/4/0) interleaved with three
// MFMA clusters (16/16/32) -> read drain (~96cyc) hides under 1306cyc of MFMA.
// Per-CU-subtile: MFMA 1306 cyc vs LDS (64KB rd @85B/cyc + 64KB wr) ~1270 ->
// MFMA-bound even serial-LDS.
// vm ledger (16 issues/subtile, ring 2): enter iter s with stage(s)=16 out;
// issue stage(s+1) -> 32; vmcnt(16) retires stage(s) exactly. stage(s) was
// issued one full iteration (~1400cyc) earlier -> covers HBM-miss latency.
// Slot reuse: stage(s+1) -> slot (s+1)&1, whose reads (iter s-1) drained at
// that iter's lgkmcnt(0). All hazards intra-wave. No cross-wave state at all.
__global__ __launch_bounds__(256, 1) void k_gemm(const uint8_t* __restrict__ xq,
                                                 const uint8_t* __restrict__ wq,
                                                 const float* __restrict__ alpha,
                                                 const float* __restrict__ gamma,
                                                 float* __restrict__ out) {
    __shared__ __align__(16) char smem[131072];  // 4 waves x (2 slots x 16KB)

    int bid = blockIdx.x;
    int wg = (bid & 7) * 128 + (bid >> 3);       // XCD-bijective (1024 % 8 == 0)
    int tm = wg >> 5, tn = wg & 31;              // 32 x 32 tiles of 256x256

    int t = threadIdx.x;
    int w = t >> 6, l = t & 63;
    int wr = w >> 1, wc = w & 1;                 // 2x2 waves, wave tile 128x128
    char* wbase = smem + w * 32768;

    // ---- private staging: 16 regions of 1KB (16 rows x 64B), 8 A + 8 B
    const uint8_t* srcb[16];
    {
        int rsub = l >> 2;                       // row within 16-row region
        int clog = (l & 3) ^ ((rsub >> 1) & 3);  // pre-swizzled source chunk
#pragma unroll
        for (int j = 0; j < 16; ++j) {
            int isB = j >> 3;
            int r = (j & 7) * 16 + rsub;         // wave-local row 0..127
            int grow = isB ? tn * 256 + wc * 128 + r
                           : tm * 256 + wr * 128 + r;
            srcb[j] = (isB ? wq : xq) + (size_t)grow * K_DIM + clog * 16;
        }
    }

    i32x4 acc[8][8];
#pragma unroll
    for (int m = 0; m < 8; ++m)
#pragma unroll
        for (int n = 0; n < 8; ++n) acc[m][n] = (i32x4){0, 0, 0, 0};

    int lrow = l & 15, kgrp = l >> 4;
    int cph = (kgrp ^ ((lrow >> 1) & 3)) * 16;   // swizzled read chunk
    int aoff[8], boff[8];
#pragma unroll
    for (int mf = 0; mf < 8; ++mf) aoff[mf] = (mf * 16 + lrow) * 64 + cph;
#pragma unroll
    for (int nf = 0; nf < 8; ++nf) boff[nf] = 8192 + (nf * 16 + lrow) * 64 + cph;

    // ---- prologue: stage subtile 0 into slot 0 (16 issues, self-paced)
#pragma unroll
    for (int j = 0; j < 16; ++j)
        load_lds16(srcb[j], wbase + j * 1024);

    for (int s = 0; s < NT; ++s) {
        char* sb = wbase + (s & 1) * 16384;
        if (s + 1 < NT) {                        // stage next subtile, other slot
            char* db = wbase + ((s + 1) & 1) * 16384;
#pragma unroll
            for (int j = 0; j < 16; ++j)
                load_lds16(srcb[j] + (size_t)(s + 1) * 64, db + j * 1024);
            asm volatile("s_waitcnt vmcnt(16)" ::: "memory");  // stage(s) landed
        } else {
            asm volatile("s_waitcnt vmcnt(0)" ::: "memory");
        }
        __builtin_amdgcn_sched_barrier(0);

        i32x4 a[8], b[8];
        // read order pinned: b0-3,a0-3 | a4-7 | b4-7  (for counted lgkm waits)
#pragma unroll
        for (int nf = 0; nf < 4; ++nf) b[nf] = *(const i32x4*)(sb + boff[nf]);
#pragma unroll
        for (int mf = 0; mf < 4; ++mf) a[mf] = *(const i32x4*)(sb + aoff[mf]);
        __builtin_amdgcn_sched_barrier(0);
#pragma unroll
        for (int mf = 4; mf < 8; ++mf) a[mf] = *(const i32x4*)(sb + aoff[mf]);
        __builtin_amdgcn_sched_barrier(0);
#pragma unroll
        for (int nf = 4; nf < 8; ++nf) b[nf] = *(const i32x4*)(sb + boff[nf]);

        asm volatile("s_waitcnt lgkmcnt(8)" ::: "memory");   // b0-3,a0-3 ready
        __builtin_amdgcn_sched_barrier(0);
        __builtin_amdgcn_s_setprio(1);
#pragma unroll
        for (int mf = 0; mf < 4; ++mf)
#pragma unroll
            for (int nf = 0; nf < 4; ++nf)
                acc[mf][nf] = __builtin_amdgcn_mfma_i32_16x16x64_i8(
                    a[mf], b[nf], acc[mf][nf], 0, 0, 0);
        __builtin_amdgcn_s_setprio(0);

        asm volatile("s_waitcnt lgkmcnt(4)" ::: "memory");   // a4-7 ready
        __builtin_amdgcn_sched_barrier(0);
        __builtin_amdgcn_s_setprio(1);
#pragma unroll
        for (int mf = 4; mf < 8; ++mf)
#pragma unroll
            for (int nf = 0; nf < 4; ++nf)
                acc[mf][nf] = __builtin_amdgcn_mfma_i32_16x16x64_i8(
                    a[mf], b[nf], acc[mf][nf], 0, 0, 0);
        __builtin_amdgcn_s_setprio(0);

        asm volatile("s_waitcnt lgkmcnt(0)" ::: "memory");   // b4-7 ready
        __builtin_amdgcn_sched_barrier(0);
        __builtin_amdgcn_s_setprio(1);
#pragma unroll
        for (int mf = 0; mf < 8; ++mf)
#pragma unroll
            for (int nf = 4; nf < 8; ++nf)
                acc[mf][nf] = __builtin_amdgcn_mfma_i32_16x16x64_i8(
                    a[mf], b[nf], acc[mf][nf], 0, 0, 0);
        __builtin_amdgcn_s_setprio(0);
    }

    // ---- epilogue: out = (float)acc * alpha[row] * gamma / 127 ----
    // C/D 16x16: col = lane&15, row = (lane>>4)*4 + reg. Direct nt stores.
    float gs = gamma[0] / QBF;
    int orow0 = tm * 256 + wr * 128 + kgrp * 4;
    int ocol0 = tn * 256 + wc * 128 + lrow;
#pragma unroll
    for (int mf = 0; mf < 8; ++mf)
#pragma unroll
        for (int r = 0; r < 4; ++r) {
            int row = orow0 + mf * 16 + r;
            float s = alpha[row] * gs;
            size_t rb = (size_t)row * N_DIM + ocol0;
#pragma unroll
            for (int nf = 0; nf < 8; ++nf)
                __builtin_nontemporal_store((float)acc[mf][nf][r] * s,
                                            out + rb + nf * 16);
        }
}

extern "C" void kernel_launch(void* const* d_in, const int* in_sizes, int n_in,
                              void* d_out, int out_size, void* d_ws, size_t ws_size,
                              hipStream_t stream) {
    const float* x  = (const float*)d_in[0];   // [4,2048,2048]
    const float* wt = (const float*)d_in[1];   // [8192,2048]
    float* out = (float*)d_out;                // [4,2048,8192] fp32

    char* ws = (char*)d_ws;
    uint8_t* xq     = (uint8_t*)ws;                     // 16,777,216 B
    uint8_t* wq     = (uint8_t*)(ws + 16777216);        // 16,777,216 B
    float* alpha    = (float*)(ws + 33554432);          // 32,768 B
    float* partial  = (float*)(ws + 33587200);          // 8,192 B
    float* gamma    = (float*)(ws + 33595392);          // 4 B

    k_abs_partial<<<2048, 256, 0, stream>>>(wt, partial);
    k_gamma<<<1, 256, 0, stream>>>(partial, gamma);
    k_quant_w<<<16384, 256, 0, stream>>>(wt, gamma, (uint*)wq);
    k_quant_x<<<8192, 256, 0, stream>>>(x, (uint*)xq, alpha);
    k_gemm<<<1024, 256, 0, stream>>>(xq, wq, alpha, gamma, out);
}